// Round 6
// baseline (499.058 us; speedup 1.0000x reference)
//
#include <hip/hip_runtime.h>
#include <math.h>
#include <float.h>

// VectorQuantize, screen-and-rescore v2 (2 kernels, inline fallback):
//  - fp16 hH MFMA screen, pair-min tracking (M1, pair-id, M2) per row
//  - certified rows (M2-M1 > THR): exact fp32 rescore of the 2 winner-pair codes
//  - uncertified rows: inline full exact fp32 scan by the whole block
// x [65536,64] f32, codebook [4096,64] f32.
// d_out (flat f32): quantized [N*64], idx [N] (as float), min_dists [N].

#define NROWS 65536
#define CDIM  64
#define KCB   4096
#define THR   0.015f   // screen err sigma ~5e-4; 30-sigma cert margin

typedef _Float16 half8 __attribute__((ext_vector_type(8)));
typedef _Float16 half4 __attribute__((ext_vector_type(4)));
typedef float f32x4 __attribute__((ext_vector_type(4)));

#define MFMA16(A, B, C) __builtin_amdgcn_mfma_f32_16x16x32_f16(A, B, C, 0, 0, 0)

// Exact fp32 distance — byte-identical arithmetic to the round-1 kernel that
// matched np with absmax 0 (2-chain fma dot, fmaf(-2,dot,x2)+c2).
__device__ __forceinline__ float exact_d2(const float* __restrict__ xr, const float* __restrict__ cb,
                                          const float* __restrict__ c2f, float x2, int k) {
    const float4* cp4 = reinterpret_cast<const float4*>(cb + (size_t)k * CDIM);
    float da = 0.f, db = 0.f;
#pragma unroll
    for (int j4 = 0; j4 < CDIM / 4; ++j4) {
        float4 cv = cp4[j4];
        da = fmaf(xr[4 * j4 + 0], cv.x, da);
        db = fmaf(xr[4 * j4 + 1], cv.y, db);
        da = fmaf(xr[4 * j4 + 2], cv.z, da);
        db = fmaf(xr[4 * j4 + 3], cv.w, db);
    }
    const float dot = da + db;
    return fmaf(-2.f, dot, x2) + c2f[k];
}

// ---- prep: fp16 codebook + c2f = ||c_k||^2 (proven in round 3) ----
__global__ __launch_bounds__(256) void prep_cb(const float* __restrict__ cb,
                                               _Float16* __restrict__ ch,
                                               float* __restrict__ c2f) {
    const int row = blockIdx.x * 16 + (threadIdx.x >> 4);
    const int j   = threadIdx.x & 15;
    const float4 v = *reinterpret_cast<const float4*>(cb + (size_t)row * CDIM + j * 4);
    float s;
    {
#pragma clang fp contract(off)
        s = v.x * v.x + v.y * v.y + v.z * v.z + v.w * v.w;
    }
    s += __shfl_xor(s, 1);
    s += __shfl_xor(s, 2);
    s += __shfl_xor(s, 4);
    s += __shfl_xor(s, 8);
    if (j == 0) c2f[row] = s;
    half4 h;
    h[0] = (_Float16)v.x; h[1] = (_Float16)v.y;
    h[2] = (_Float16)v.z; h[3] = (_Float16)v.w;
    *reinterpret_cast<half4*>(ch + (size_t)row * CDIM + j * 4) = h;
}

// ---- main: screen + certify + rescore + inline exact fallback + gather ----
__global__ __launch_bounds__(256, 2) void vq_screen(
    const float* __restrict__ x, const float* __restrict__ cb,
    const _Float16* __restrict__ ch, const float* __restrict__ c2f,
    float* __restrict__ outq, float* __restrict__ outidx, float* __restrict__ outd) {

    const int tid  = threadIdx.x;
    const int lane = tid & 63;
    const int wv   = __builtin_amdgcn_readfirstlane(tid >> 6);
    const int lrow = lane & 15;
    const int lhi  = lane >> 4;
    const int n0   = blockIdx.x * 64;
    const int kbase = wv * 1024;        // each wave screens a k-quarter

    __shared__ float Lm1[4][64], Lm2[4][64];
    __shared__ int   Li[4][64];
    __shared__ int   Lwin[64];
    __shared__ int   s_cnt;
    __shared__ int   s_list[64];
    __shared__ float swd[4];
    __shared__ int   swi[4];
    if (tid == 0) s_cnt = 0;

    // A fragments (x rows n0..n0+63; layout proven rounds 2-3)
    half8 afh[4][2];
#pragma unroll
    for (int st = 0; st < 4; ++st) {
#pragma unroll
        for (int cs = 0; cs < 2; ++cs) {
            const float* xp = x + (size_t)(n0 + st * 16 + lrow) * CDIM + cs * 32 + lhi * 8;
            const float4 a = *reinterpret_cast<const float4*>(xp);
            const float4 b = *reinterpret_cast<const float4*>(xp + 4);
            afh[st][cs][0] = (_Float16)a.x; afh[st][cs][1] = (_Float16)a.y;
            afh[st][cs][2] = (_Float16)a.z; afh[st][cs][3] = (_Float16)a.w;
            afh[st][cs][4] = (_Float16)b.x; afh[st][cs][5] = (_Float16)b.y;
            afh[st][cs][6] = (_Float16)b.z; afh[st][cs][7] = (_Float16)b.w;
        }
    }

    const f32x4 zz = {0.f, 0.f, 0.f, 0.f};   // loop-invariant MFMA C-input
    float M1[4][4], M2[4][4];
    int   ip[4][4];
#pragma unroll
    for (int st = 0; st < 4; ++st)
#pragma unroll
        for (int r = 0; r < 4; ++r) { M1[st][r] = FLT_MAX; M2[st][r] = FLT_MAX; ip[st][r] = 0; }

    const _Float16* pb  = ch + (size_t)(kbase + lrow) * CDIM + lhi * 8;
    const float*    pc2 = c2f + kbase + lrow;

    for (int kt2 = 0; kt2 < 32; ++kt2) {     // 2 kt (32 codes) per iteration
        const _Float16* p0 = pb + (size_t)kt2 * 2048;   // 2 kt * 16 codes * 64 halfs
        const half8 b00 = *reinterpret_cast<const half8*>(p0);
        const half8 b01 = *reinterpret_cast<const half8*>(p0 + 32);
        const half8 b10 = *reinterpret_cast<const half8*>(p0 + 1024);
        const half8 b11 = *reinterpret_cast<const half8*>(p0 + 1024 + 32);
        const float c2a = pc2[kt2 * 32];
        const float c2b = pc2[kt2 * 32 + 16];

        f32x4 a0[4], a1[4];
#pragma unroll
        for (int st = 0; st < 4; ++st) {
            a0[st] = MFMA16(afh[st][0], b00, zz);
            a1[st] = MFMA16(afh[st][0], b10, zz);
        }
#pragma unroll
        for (int st = 0; st < 4; ++st) {
            a0[st] = MFMA16(afh[st][1], b01, a0[st]);
            a1[st] = MFMA16(afh[st][1], b11, a1[st]);
        }

#pragma unroll
        for (int st = 0; st < 4; ++st)
#pragma unroll
            for (int r = 0; r < 4; ++r) {
                const float dd0 = fmaf(-2.f, a0[st][r], c2a);
                const float dd1 = fmaf(-2.f, a1[st][r], c2b);
                const float pm  = fminf(dd0, dd1);
                M2[st][r] = fminf(M2[st][r], fmaxf(pm, M1[st][r]));  // uses OLD M1
                const bool c = pm < M1[st][r];                        // strict <
                ip[st][r] = c ? kt2 : ip[st][r];
                M1[st][r] = fminf(M1[st][r], pm);
            }
    }

    // butterfly-merge the 16 k-slice lanes (lrow) of each lhi group
#pragma unroll
    for (int st = 0; st < 4; ++st)
#pragma unroll
        for (int r = 0; r < 4; ++r) {
            int   i1k = kbase + ip[st][r] * 32 + lrow;   // pair-base code id
            float m1  = M1[st][r], m2 = M2[st][r];
#pragma unroll
            for (int msk = 1; msk <= 8; msk <<= 1) {
                const float o1 = __shfl_xor(m1, msk);
                const int   oi = __shfl_xor(i1k, msk);
                const float o2 = __shfl_xor(m2, msk);
                m2 = fminf(fminf(m2, o2), fmaxf(m1, o1));
                const bool t = (o1 < m1) || (o1 == m1 && oi < i1k);
                i1k = t ? oi : i1k;
                m1  = fminf(m1, o1);
            }
            if (lrow == 0) {
                const int rw = st * 16 + lhi * 4 + r;
                Lm1[wv][rw] = m1; Lm2[wv][rw] = m2; Li[wv][rw] = i1k;
            }
        }
    __syncthreads();

    if (tid < 64) {
        float m1 = Lm1[0][tid], m2 = Lm2[0][tid];
        int   i1 = Li[0][tid];
#pragma unroll
        for (int w = 1; w < 4; ++w) {
            const float w1 = Lm1[w][tid], w2 = Lm2[w][tid];
            const int   wi = Li[w][tid];
            m2 = fminf(fminf(m2, w2), fmaxf(m1, w1));   // uses OLD m1
            if (w1 < m1) { m1 = w1; i1 = wi; }          // k-ranges ascend with w
        }
        const int row = n0 + tid;

        // exact rescore of the winner pair {i1, i1+16}
        float xr[CDIM];
        const float4* xp = reinterpret_cast<const float4*>(x + (size_t)row * CDIM);
#pragma unroll
        for (int j = 0; j < CDIM / 4; ++j) {
            const float4 v = xp[j];
            xr[4 * j + 0] = v.x; xr[4 * j + 1] = v.y;
            xr[4 * j + 2] = v.z; xr[4 * j + 3] = v.w;
        }
        float x2 = 0.f;
        {
#pragma clang fp contract(off)
#pragma unroll
            for (int j = 0; j < CDIM; ++j) x2 += xr[j] * xr[j];
        }
        const float d2a = exact_d2(xr, cb, c2f, x2, i1);
        const float d2b = exact_d2(xr, cb, c2f, x2, i1 + 16);
        int win; float d2w;
        if (d2b < d2a) { win = i1 + 16; d2w = d2b; }
        else           { win = i1;      d2w = d2a; }   // tie -> smaller index

        if (m2 - m1 > THR) {                 // certified: argmin is in the pair
            outidx[row] = (float)win;
            outd[row]   = sqrtf(fmaxf(d2w, 0.f));
            Lwin[tid]   = win;
        } else {                             // suspect: exact scan below
            const int s = atomicAdd(&s_cnt, 1);
            s_list[s] = tid;
        }
    }
    __syncthreads();

    // inline exact fallback: whole block scans all 4096 codes per suspect row
    const int ns = s_cnt;
    for (int s = 0; s < ns; ++s) {
        const int rl  = s_list[s];
        const int row = n0 + rl;
        float xr[CDIM];
        const float4* xp = reinterpret_cast<const float4*>(x + (size_t)row * CDIM);
#pragma unroll
        for (int j = 0; j < CDIM / 4; ++j) {
            const float4 v = xp[j];
            xr[4 * j + 0] = v.x; xr[4 * j + 1] = v.y;
            xr[4 * j + 2] = v.z; xr[4 * j + 3] = v.w;
        }
        float x2 = 0.f;
        {
#pragma clang fp contract(off)
#pragma unroll
            for (int j = 0; j < CDIM; ++j) x2 += xr[j] * xr[j];
        }
        float bd = FLT_MAX;
        int   bi = 0;
        for (int j = 0; j < 16; ++j) {
            const int k = j * 256 + tid;                 // ascending per thread
            const float d2v = exact_d2(xr, cb, c2f, x2, k);
            if (d2v < bd) { bd = d2v; bi = k; }          // strict <
        }
#pragma unroll
        for (int msk = 1; msk <= 32; msk <<= 1) {
            const float od = __shfl_xor(bd, msk);
            const int   oi = __shfl_xor(bi, msk);
            if (od < bd || (od == bd && oi < bi)) { bd = od; bi = oi; }
        }
        if (lane == 0) { swd[wv] = bd; swi[wv] = bi; }
        __syncthreads();
        if (tid == 0) {
            float bb = swd[0]; int bk = swi[0];
#pragma unroll
            for (int w = 1; w < 4; ++w)
                if (swd[w] < bb || (swd[w] == bb && swi[w] < bk)) { bb = swd[w]; bk = swi[w]; }
            outidx[row] = (float)bk;
            outd[row]   = sqrtf(fmaxf(bb, 0.f));
            Lwin[rl]    = bk;
        }
        __syncthreads();
    }

    // gather quantized = codebook[win]
    {
        const int r   = tid >> 2;
        const int seg = tid & 3;
        const int b   = Lwin[r];
        const float4* src = reinterpret_cast<const float4*>(cb + (size_t)b * CDIM) + seg * 4;
        float4* dst = reinterpret_cast<float4*>(outq + (size_t)(n0 + r) * CDIM) + seg * 4;
#pragma unroll
        for (int t = 0; t < 4; ++t) dst[t] = src[t];
    }
}

extern "C" void kernel_launch(void* const* d_in, const int* in_sizes, int n_in,
                              void* d_out, int out_size, void* d_ws, size_t ws_size,
                              hipStream_t stream) {
    const float* x  = (const float*)d_in[0];
    const float* cb = (const float*)d_in[1];
    float* outq   = (float*)d_out;
    float* outidx = outq + (size_t)NROWS * CDIM;
    float* outd   = outidx + NROWS;

    char* ws = (char*)d_ws;
    _Float16* ch  = (_Float16*)ws;              // 512 KB
    float*    c2f = (float*)(ws + 512 * 1024);  // 16 KB

    prep_cb<<<KCB / 16, 256, 0, stream>>>(cb, ch, c2f);
    vq_screen<<<NROWS / 64, 256, 0, stream>>>(x, cb, ch, c2f, outq, outidx, outd);
}

// Round 8
// 293.516 us; speedup vs baseline: 1.7003x; 1.7003x over previous
//
#include <hip/hip_runtime.h>
#include <math.h>
#include <float.h>

// VectorQuantize, screen-and-rescore v3:
//  - 3-product fp16-split MFMA screen (hH + S1*(hM + mH); only mM dropped)
//    -> sound cert threshold THR=1.5e-3, suspect rate ~0.5% (was 5% at fp16-only)
//  - pair-min tracking with pair-id PACKED in M1's low 5 mantissa bits
//  - certified rows: exact fp32 rescore of the 2 winner-pair codes
//  - suspects: inline full exact fp32 scan by the whole block (rare now)
// x [65536,64] f32, codebook [4096,64] f32.
// d_out (flat f32): quantized [N*64], idx [N] (as float), min_dists [N].

#define NROWS 65536
#define CDIM  64
#define KCB   4096
#define RSCALE 4096.0f
#define S1 (1.0f/4096.0f)
#define THR 1.5e-3f   // >= 2*(mM 2.6e-5 + acc-round 1e-4 + dd-fma 1.5e-5 + pack 2.4e-4)

typedef _Float16 half8 __attribute__((ext_vector_type(8)));
typedef _Float16 half4 __attribute__((ext_vector_type(4)));
typedef float f32x4 __attribute__((ext_vector_type(4)));

#define MFMA16(A, B, C) __builtin_amdgcn_mfma_f32_16x16x32_f16(A, B, C, 0, 0, 0)

// Exact fp32 distance — byte-identical arithmetic to the round-1 kernel that
// matched np with absmax 0 (2-chain fma dot, fmaf(-2,dot,x2)+c2).
__device__ __forceinline__ float exact_d2(const float* __restrict__ xr, const float* __restrict__ cb,
                                          const float* __restrict__ c2f, float x2, int k) {
    const float4* cp4 = reinterpret_cast<const float4*>(cb + (size_t)k * CDIM);
    float da = 0.f, db = 0.f;
#pragma unroll
    for (int j4 = 0; j4 < CDIM / 4; ++j4) {
        float4 cv = cp4[j4];
        da = fmaf(xr[4 * j4 + 0], cv.x, da);
        db = fmaf(xr[4 * j4 + 1], cv.y, db);
        da = fmaf(xr[4 * j4 + 2], cv.z, da);
        db = fmaf(xr[4 * j4 + 3], cv.w, db);
    }
    const float dot = da + db;
    return fmaf(-2.f, dot, x2) + c2f[k];
}

// ---- prep: fp16 split codebook (ch, cm) + c2f = ||c_k||^2 ----
__global__ __launch_bounds__(256) void prep_cb(const float* __restrict__ cb,
                                               _Float16* __restrict__ ch,
                                               _Float16* __restrict__ cm,
                                               float* __restrict__ c2f) {
    const int row = blockIdx.x * 16 + (threadIdx.x >> 4);
    const int j   = threadIdx.x & 15;
    const float4 v = *reinterpret_cast<const float4*>(cb + (size_t)row * CDIM + j * 4);
    float s;
    {
#pragma clang fp contract(off)
        s = v.x * v.x + v.y * v.y + v.z * v.z + v.w * v.w;
    }
    s += __shfl_xor(s, 1);
    s += __shfl_xor(s, 2);
    s += __shfl_xor(s, 4);
    s += __shfl_xor(s, 8);
    if (j == 0) c2f[row] = s;
    float e[4] = {v.x, v.y, v.z, v.w};
    half4 h, m;
#pragma unroll
    for (int t = 0; t < 4; ++t) {
        _Float16 hv = (_Float16)e[t];
        h[t] = hv;
        m[t] = (_Float16)((e[t] - (float)hv) * RSCALE);  // exact residual, scaled
    }
    *reinterpret_cast<half4*>(ch + (size_t)row * CDIM + j * 4) = h;
    *reinterpret_cast<half4*>(cm + (size_t)row * CDIM + j * 4) = m;
}

// ---- main: 3-product screen + certify + rescore + inline fallback + gather ----
__global__ __launch_bounds__(256, 2) void vq_screen(
    const float* __restrict__ x, const float* __restrict__ cb,
    const _Float16* __restrict__ ch, const _Float16* __restrict__ cm,
    const float* __restrict__ c2f,
    float* __restrict__ outq, float* __restrict__ outidx, float* __restrict__ outd) {

    const int tid  = threadIdx.x;
    const int lane = tid & 63;
    const int wv   = __builtin_amdgcn_readfirstlane(tid >> 6);
    const int lrow = lane & 15;
    const int lhi  = lane >> 4;
    const int n0   = blockIdx.x * 64;
    const int kbase = wv * 1024;        // each wave screens a k-quarter

    __shared__ float Lm1[4][64], Lm2[4][64];
    __shared__ int   Li[4][64];
    __shared__ int   Lwin[64];
    __shared__ int   s_cnt;
    __shared__ int   s_list[64];
    __shared__ float swd[4];
    __shared__ int   swi[4];
    if (tid == 0) s_cnt = 0;

    // A fragments: h and scaled residual m (x rows n0..n0+63; layout HW-proven r2/3/6)
    half8 afh[4][2], afm[4][2];
#pragma unroll
    for (int st = 0; st < 4; ++st) {
#pragma unroll
        for (int cs = 0; cs < 2; ++cs) {
            const float* xp = x + (size_t)(n0 + st * 16 + lrow) * CDIM + cs * 32 + lhi * 8;
            const float4 a = *reinterpret_cast<const float4*>(xp);
            const float4 b = *reinterpret_cast<const float4*>(xp + 4);
            float e[8] = {a.x, a.y, a.z, a.w, b.x, b.y, b.z, b.w};
#pragma unroll
            for (int jj = 0; jj < 8; ++jj) {
                _Float16 hv = (_Float16)e[jj];
                afh[st][cs][jj] = hv;
                afm[st][cs][jj] = (_Float16)((e[jj] - (float)hv) * RSCALE);
            }
        }
    }

    const f32x4 zz = {0.f, 0.f, 0.f, 0.f};
    float M1[4][4], M2[4][4];     // M1 carries pair-id in low 5 mantissa bits
#pragma unroll
    for (int st = 0; st < 4; ++st)
#pragma unroll
        for (int r = 0; r < 4; ++r) { M1[st][r] = FLT_MAX; M2[st][r] = FLT_MAX; }

    const _Float16* phb = ch + (size_t)(kbase + lrow) * CDIM + lhi * 8;
    const _Float16* pmb = cm + (size_t)(kbase + lrow) * CDIM + lhi * 8;
    const float*    pc2 = c2f + kbase + lrow;

    for (int kt2 = 0; kt2 < 32; ++kt2) {     // 2 code-tiles (32 codes) per iter
        const float c2a = pc2[kt2 * 32];
        const float c2b = pc2[kt2 * 32 + 16];

        // ---- tile 0 ----
        float t0[4][4];
        {
            const _Float16* p0 = phb + (size_t)kt2 * 2048;
            const _Float16* q0 = pmb + (size_t)kt2 * 2048;
            const half8 bh0 = *reinterpret_cast<const half8*>(p0);
            const half8 bh1 = *reinterpret_cast<const half8*>(p0 + 32);
            const half8 bm0 = *reinterpret_cast<const half8*>(q0);
            const half8 bm1 = *reinterpret_cast<const half8*>(q0 + 32);
            f32x4 a0[4], a1[4];
#pragma unroll
            for (int st = 0; st < 4; ++st) {
                a0[st] = MFMA16(afh[st][0], bh0, zz);
                a1[st] = MFMA16(afh[st][0], bm0, zz);
            }
#pragma unroll
            for (int st = 0; st < 4; ++st) {
                a0[st] = MFMA16(afh[st][1], bh1, a0[st]);
                a1[st] = MFMA16(afh[st][1], bm1, a1[st]);
            }
#pragma unroll
            for (int st = 0; st < 4; ++st) {
                a1[st] = MFMA16(afm[st][0], bh0, a1[st]);
                a1[st] = MFMA16(afm[st][1], bh1, a1[st]);
            }
#pragma unroll
            for (int st = 0; st < 4; ++st)
#pragma unroll
                for (int r = 0; r < 4; ++r)
                    t0[st][r] = fmaf(-2.f * S1, a1[st][r], fmaf(-2.f, a0[st][r], c2a));
        }
        // ---- tile 1 + pair update ----
        {
            const _Float16* p1 = phb + (size_t)kt2 * 2048 + 1024;
            const _Float16* q1 = pmb + (size_t)kt2 * 2048 + 1024;
            const half8 bh0 = *reinterpret_cast<const half8*>(p1);
            const half8 bh1 = *reinterpret_cast<const half8*>(p1 + 32);
            const half8 bm0 = *reinterpret_cast<const half8*>(q1);
            const half8 bm1 = *reinterpret_cast<const half8*>(q1 + 32);
            f32x4 a0[4], a1[4];
#pragma unroll
            for (int st = 0; st < 4; ++st) {
                a0[st] = MFMA16(afh[st][0], bh0, zz);
                a1[st] = MFMA16(afh[st][0], bm0, zz);
            }
#pragma unroll
            for (int st = 0; st < 4; ++st) {
                a0[st] = MFMA16(afh[st][1], bh1, a0[st]);
                a1[st] = MFMA16(afh[st][1], bm1, a1[st]);
            }
#pragma unroll
            for (int st = 0; st < 4; ++st) {
                a1[st] = MFMA16(afm[st][0], bh0, a1[st]);
                a1[st] = MFMA16(afm[st][1], bh1, a1[st]);
            }
#pragma unroll
            for (int st = 0; st < 4; ++st)
#pragma unroll
                for (int r = 0; r < 4; ++r) {
                    const float dd1 = fmaf(-2.f * S1, a1[st][r], fmaf(-2.f, a0[st][r], c2b));
                    const float pm  = fminf(t0[st][r], dd1);
                    // pack pair-id (kt2, 5 bits) into low mantissa bits
                    const float pmp = __uint_as_float((__float_as_uint(pm) & ~31u) | (unsigned)kt2);
                    M2[st][r] = fminf(M2[st][r], fmaxf(pmp, M1[st][r]));  // OLD M1
                    M1[st][r] = fminf(M1[st][r], pmp);
                }
        }
    }

    // butterfly-merge the 16 code-slot lanes (lrow) of each lhi group
#pragma unroll
    for (int st = 0; st < 4; ++st)
#pragma unroll
        for (int r = 0; r < 4; ++r) {
            const unsigned kt2e = __float_as_uint(M1[st][r]) & 31u;
            int   i1k = kbase + (int)kt2e * 32 + lrow;   // pair-base code id
            float m1  = M1[st][r], m2 = M2[st][r];
#pragma unroll
            for (int msk = 1; msk <= 8; msk <<= 1) {
                const float o1 = __shfl_xor(m1, msk);
                const int   oi = __shfl_xor(i1k, msk);
                const float o2 = __shfl_xor(m2, msk);
                m2 = fminf(fminf(m2, o2), fmaxf(m1, o1));  // packed tie -> m2==m1
                const bool t = (o1 < m1) || (o1 == m1 && oi < i1k);
                i1k = t ? oi : i1k;
                m1  = fminf(m1, o1);
            }
            if (lrow == 0) {
                const int rw = st * 16 + lhi * 4 + r;
                Lm1[wv][rw] = m1; Lm2[wv][rw] = m2; Li[wv][rw] = i1k;
            }
        }
    __syncthreads();

    if (tid < 64) {
        float m1 = Lm1[0][tid], m2 = Lm2[0][tid];
        int   i1 = Li[0][tid];
#pragma unroll
        for (int w = 1; w < 4; ++w) {
            const float w1 = Lm1[w][tid], w2 = Lm2[w][tid];
            const int   wi = Li[w][tid];
            m2 = fminf(fminf(m2, w2), fmaxf(m1, w1));   // uses OLD m1
            if (w1 < m1) { m1 = w1; i1 = wi; }          // k-ranges ascend with w
        }
        const int row = n0 + tid;

        // exact rescore of the winner pair {i1, i1+16}
        float xr[CDIM];
        const float4* xp = reinterpret_cast<const float4*>(x + (size_t)row * CDIM);
#pragma unroll
        for (int j = 0; j < CDIM / 4; ++j) {
            const float4 v = xp[j];
            xr[4 * j + 0] = v.x; xr[4 * j + 1] = v.y;
            xr[4 * j + 2] = v.z; xr[4 * j + 3] = v.w;
        }
        float x2 = 0.f;
        {
#pragma clang fp contract(off)
#pragma unroll
            for (int j = 0; j < CDIM; ++j) x2 += xr[j] * xr[j];
        }
        const float d2a = exact_d2(xr, cb, c2f, x2, i1);
        const float d2b = exact_d2(xr, cb, c2f, x2, i1 + 16);
        int win; float d2w;
        if (d2b < d2a) { win = i1 + 16; d2w = d2b; }
        else           { win = i1;      d2w = d2a; }   // tie -> smaller index

        if (m2 - m1 > THR) {                 // certified: argmin is in the pair
            outidx[row] = (float)win;
            outd[row]   = sqrtf(fmaxf(d2w, 0.f));
            Lwin[tid]   = win;
        } else {                             // suspect: exact scan below
            const int s = atomicAdd(&s_cnt, 1);
            s_list[s] = tid;
        }
    }
    __syncthreads();

    // inline exact fallback: whole block scans all 4096 codes per suspect row
    const int ns = s_cnt;
    for (int s = 0; s < ns; ++s) {
        const int rl  = s_list[s];
        const int row = n0 + rl;
        float xr[CDIM];
        const float4* xp = reinterpret_cast<const float4*>(x + (size_t)row * CDIM);
#pragma unroll
        for (int j = 0; j < CDIM / 4; ++j) {
            const float4 v = xp[j];
            xr[4 * j + 0] = v.x; xr[4 * j + 1] = v.y;
            xr[4 * j + 2] = v.z; xr[4 * j + 3] = v.w;
        }
        float x2 = 0.f;
        {
#pragma clang fp contract(off)
#pragma unroll
            for (int j = 0; j < CDIM; ++j) x2 += xr[j] * xr[j];
        }
        float bd = FLT_MAX;
        int   bi = 0;
        for (int j = 0; j < 16; ++j) {
            const int k = j * 256 + tid;                 // ascending per thread
            const float d2v = exact_d2(xr, cb, c2f, x2, k);
            if (d2v < bd) { bd = d2v; bi = k; }          // strict <
        }
#pragma unroll
        for (int msk = 1; msk <= 32; msk <<= 1) {
            const float od = __shfl_xor(bd, msk);
            const int   oi = __shfl_xor(bi, msk);
            if (od < bd || (od == bd && oi < bi)) { bd = od; bi = oi; }
        }
        if (lane == 0) { swd[wv] = bd; swi[wv] = bi; }
        __syncthreads();
        if (tid == 0) {
            float bb = swd[0]; int bk = swi[0];
#pragma unroll
            for (int w = 1; w < 4; ++w)
                if (swd[w] < bb || (swd[w] == bb && swi[w] < bk)) { bb = swd[w]; bk = swi[w]; }
            outidx[row] = (float)bk;
            outd[row]   = sqrtf(fmaxf(bb, 0.f));
            Lwin[rl]    = bk;
        }
        __syncthreads();
    }

    // gather quantized = codebook[win]
    {
        const int r   = tid >> 2;
        const int seg = tid & 3;
        const int b   = Lwin[r];
        const float4* src = reinterpret_cast<const float4*>(cb + (size_t)b * CDIM) + seg * 4;
        float4* dst = reinterpret_cast<float4*>(outq + (size_t)(n0 + r) * CDIM) + seg * 4;
#pragma unroll
        for (int t = 0; t < 4; ++t) dst[t] = src[t];
    }
}

extern "C" void kernel_launch(void* const* d_in, const int* in_sizes, int n_in,
                              void* d_out, int out_size, void* d_ws, size_t ws_size,
                              hipStream_t stream) {
    const float* x  = (const float*)d_in[0];
    const float* cb = (const float*)d_in[1];
    float* outq   = (float*)d_out;
    float* outidx = outq + (size_t)NROWS * CDIM;
    float* outd   = outidx + NROWS;

    char* ws = (char*)d_ws;
    _Float16* ch  = (_Float16*)ws;                        // 512 KB
    _Float16* cm  = (_Float16*)(ws + 512 * 1024);         // 512 KB
    float*    c2f = (float*)(ws + 1024 * 1024);           // 16 KB

    prep_cb<<<KCB / 16, 256, 0, stream>>>(cb, ch, cm, c2f);
    vq_screen<<<NROWS / 64, 256, 0, stream>>>(x, cb, ch, cm, c2f, outq, outidx, outd);
}

// Round 9
// 288.138 us; speedup vs baseline: 1.7320x; 1.0187x over previous
//
#include <hip/hip_runtime.h>
#include <math.h>
#include <float.h>

// VectorQuantize, screen-and-rescore v4 = v3 + register-double-buffered
// B-fragment prefetch (the only change vs round-8's absmax-0 kernel).
//  - 3-product fp16-split MFMA screen (hH + S1*(hM + mH); only mM dropped)
//  - pair-min tracking, pair-id packed in M1's low 5 mantissa bits
//  - certified rows (m2-m1 > THR): exact fp32 rescore of winner pair
//  - suspects: inline full exact fp32 scan by the whole block
// x [65536,64] f32, codebook [4096,64] f32.
// d_out (flat f32): quantized [N*64], idx [N] (as float), min_dists [N].

#define NROWS 65536
#define CDIM  64
#define KCB   4096
#define RSCALE 4096.0f
#define S1 (1.0f/4096.0f)
#define THR 1.5e-3f   // >= 2*(mM 2.6e-5 + acc-round 1e-4 + dd-fma 1.5e-5 + pack 2.4e-4)

typedef _Float16 half8 __attribute__((ext_vector_type(8)));
typedef _Float16 half4 __attribute__((ext_vector_type(4)));
typedef float f32x4 __attribute__((ext_vector_type(4)));

#define MFMA16(A, B, C) __builtin_amdgcn_mfma_f32_16x16x32_f16(A, B, C, 0, 0, 0)

__device__ __forceinline__ float exact_d2(const float* __restrict__ xr, const float* __restrict__ cb,
                                          const float* __restrict__ c2f, float x2, int k) {
    const float4* cp4 = reinterpret_cast<const float4*>(cb + (size_t)k * CDIM);
    float da = 0.f, db = 0.f;
#pragma unroll
    for (int j4 = 0; j4 < CDIM / 4; ++j4) {
        float4 cv = cp4[j4];
        da = fmaf(xr[4 * j4 + 0], cv.x, da);
        db = fmaf(xr[4 * j4 + 1], cv.y, db);
        da = fmaf(xr[4 * j4 + 2], cv.z, da);
        db = fmaf(xr[4 * j4 + 3], cv.w, db);
    }
    const float dot = da + db;
    return fmaf(-2.f, dot, x2) + c2f[k];
}

// ---- prep: fp16 split codebook (ch, cm) + c2f = ||c_k||^2 ----
__global__ __launch_bounds__(256) void prep_cb(const float* __restrict__ cb,
                                               _Float16* __restrict__ ch,
                                               _Float16* __restrict__ cm,
                                               float* __restrict__ c2f) {
    const int row = blockIdx.x * 16 + (threadIdx.x >> 4);
    const int j   = threadIdx.x & 15;
    const float4 v = *reinterpret_cast<const float4*>(cb + (size_t)row * CDIM + j * 4);
    float s;
    {
#pragma clang fp contract(off)
        s = v.x * v.x + v.y * v.y + v.z * v.z + v.w * v.w;
    }
    s += __shfl_xor(s, 1);
    s += __shfl_xor(s, 2);
    s += __shfl_xor(s, 4);
    s += __shfl_xor(s, 8);
    if (j == 0) c2f[row] = s;
    float e[4] = {v.x, v.y, v.z, v.w};
    half4 h, m;
#pragma unroll
    for (int t = 0; t < 4; ++t) {
        _Float16 hv = (_Float16)e[t];
        h[t] = hv;
        m[t] = (_Float16)((e[t] - (float)hv) * RSCALE);  // exact residual, scaled
    }
    *reinterpret_cast<half4*>(ch + (size_t)row * CDIM + j * 4) = h;
    *reinterpret_cast<half4*>(cm + (size_t)row * CDIM + j * 4) = m;
}

// ---- main: prefetched 3-product screen + certify + rescore + fallback ----
__global__ __launch_bounds__(256, 2) void vq_screen(
    const float* __restrict__ x, const float* __restrict__ cb,
    const _Float16* __restrict__ ch, const _Float16* __restrict__ cm,
    const float* __restrict__ c2f,
    float* __restrict__ outq, float* __restrict__ outidx, float* __restrict__ outd) {

    const int tid  = threadIdx.x;
    const int lane = tid & 63;
    const int wv   = __builtin_amdgcn_readfirstlane(tid >> 6);
    const int lrow = lane & 15;
    const int lhi  = lane >> 4;
    const int n0   = blockIdx.x * 64;
    const int kbase = wv * 1024;        // each wave screens a k-quarter

    __shared__ float Lm1[4][64], Lm2[4][64];
    __shared__ int   Li[4][64];
    __shared__ int   Lwin[64];
    __shared__ int   s_cnt;
    __shared__ int   s_list[64];
    __shared__ float swd[4];
    __shared__ int   swi[4];
    if (tid == 0) s_cnt = 0;

    const _Float16* phb = ch + (size_t)(kbase + lrow) * CDIM + lhi * 8;
    const _Float16* pmb = cm + (size_t)(kbase + lrow) * CDIM + lhi * 8;
    const float*    pc2 = c2f + kbase + lrow;

    // prefetch registers (next iteration's B fragments + c2)
    half8 nh0, nh1, nh2, nh3, nm0, nm1, nm2, nm3;
    float nc2a, nc2b;
#define LOADB(K2) do { \
        const _Float16* _p = phb + (size_t)(K2) * 2048; \
        const _Float16* _q = pmb + (size_t)(K2) * 2048; \
        nh0 = *reinterpret_cast<const half8*>(_p); \
        nh1 = *reinterpret_cast<const half8*>(_p + 32); \
        nh2 = *reinterpret_cast<const half8*>(_p + 1024); \
        nh3 = *reinterpret_cast<const half8*>(_p + 1024 + 32); \
        nm0 = *reinterpret_cast<const half8*>(_q); \
        nm1 = *reinterpret_cast<const half8*>(_q + 32); \
        nm2 = *reinterpret_cast<const half8*>(_q + 1024); \
        nm3 = *reinterpret_cast<const half8*>(_q + 1024 + 32); \
        nc2a = pc2[(K2) * 32]; \
        nc2b = pc2[(K2) * 32 + 16]; \
    } while (0)

    LOADB(0);   // issue first B-tile loads; latency hides under A-setup below

    // A fragments: h and scaled residual m (x rows n0..n0+63; layout HW-proven)
    half8 afh[4][2], afm[4][2];
#pragma unroll
    for (int st = 0; st < 4; ++st) {
#pragma unroll
        for (int cs = 0; cs < 2; ++cs) {
            const float* xp = x + (size_t)(n0 + st * 16 + lrow) * CDIM + cs * 32 + lhi * 8;
            const float4 a = *reinterpret_cast<const float4*>(xp);
            const float4 b = *reinterpret_cast<const float4*>(xp + 4);
            float e[8] = {a.x, a.y, a.z, a.w, b.x, b.y, b.z, b.w};
#pragma unroll
            for (int jj = 0; jj < 8; ++jj) {
                _Float16 hv = (_Float16)e[jj];
                afh[st][cs][jj] = hv;
                afm[st][cs][jj] = (_Float16)((e[jj] - (float)hv) * RSCALE);
            }
        }
    }

    const f32x4 zz = {0.f, 0.f, 0.f, 0.f};
    float M1[4][4], M2[4][4];     // M1 carries pair-id in low 5 mantissa bits
#pragma unroll
    for (int st = 0; st < 4; ++st)
#pragma unroll
        for (int r = 0; r < 4; ++r) { M1[st][r] = FLT_MAX; M2[st][r] = FLT_MAX; }

    for (int kt2 = 0; kt2 < 32; ++kt2) {     // 2 code-tiles (32 codes) per iter
        // rotate prefetched values into current-use copies
        const half8 bh0 = nh0, bh1 = nh1, bh2 = nh2, bh3 = nh3;
        const half8 bm0 = nm0, bm1 = nm1, bm2 = nm2, bm3 = nm3;
        const float c2a = nc2a, c2b = nc2b;
        if (kt2 < 31) LOADB(kt2 + 1);        // issue next tile's loads NOW

        // ---- tile 0 ----
        float t0[4][4];
        {
            f32x4 a0[4], a1[4];
#pragma unroll
            for (int st = 0; st < 4; ++st) {
                a0[st] = MFMA16(afh[st][0], bh0, zz);
                a1[st] = MFMA16(afh[st][0], bm0, zz);
            }
#pragma unroll
            for (int st = 0; st < 4; ++st) {
                a0[st] = MFMA16(afh[st][1], bh1, a0[st]);
                a1[st] = MFMA16(afh[st][1], bm1, a1[st]);
            }
#pragma unroll
            for (int st = 0; st < 4; ++st) {
                a1[st] = MFMA16(afm[st][0], bh0, a1[st]);
                a1[st] = MFMA16(afm[st][1], bh1, a1[st]);
            }
#pragma unroll
            for (int st = 0; st < 4; ++st)
#pragma unroll
                for (int r = 0; r < 4; ++r)
                    t0[st][r] = fmaf(-2.f * S1, a1[st][r], fmaf(-2.f, a0[st][r], c2a));
        }
        // ---- tile 1 + pair update ----
        {
            f32x4 a0[4], a1[4];
#pragma unroll
            for (int st = 0; st < 4; ++st) {
                a0[st] = MFMA16(afh[st][0], bh2, zz);
                a1[st] = MFMA16(afh[st][0], bm2, zz);
            }
#pragma unroll
            for (int st = 0; st < 4; ++st) {
                a0[st] = MFMA16(afh[st][1], bh3, a0[st]);
                a1[st] = MFMA16(afh[st][1], bm3, a1[st]);
            }
#pragma unroll
            for (int st = 0; st < 4; ++st) {
                a1[st] = MFMA16(afm[st][0], bh2, a1[st]);
                a1[st] = MFMA16(afm[st][1], bh3, a1[st]);
            }
#pragma unroll
            for (int st = 0; st < 4; ++st)
#pragma unroll
                for (int r = 0; r < 4; ++r) {
                    const float dd1 = fmaf(-2.f * S1, a1[st][r], fmaf(-2.f, a0[st][r], c2b));
                    const float pm  = fminf(t0[st][r], dd1);
                    // pack pair-id (kt2, 5 bits) into low mantissa bits
                    const float pmp = __uint_as_float((__float_as_uint(pm) & ~31u) | (unsigned)kt2);
                    M2[st][r] = fminf(M2[st][r], fmaxf(pmp, M1[st][r]));  // OLD M1
                    M1[st][r] = fminf(M1[st][r], pmp);
                }
        }
    }
#undef LOADB

    // butterfly-merge the 16 code-slot lanes (lrow) of each lhi group
#pragma unroll
    for (int st = 0; st < 4; ++st)
#pragma unroll
        for (int r = 0; r < 4; ++r) {
            const unsigned kt2e = __float_as_uint(M1[st][r]) & 31u;
            int   i1k = kbase + (int)kt2e * 32 + lrow;   // pair-base code id
            float m1  = M1[st][r], m2 = M2[st][r];
#pragma unroll
            for (int msk = 1; msk <= 8; msk <<= 1) {
                const float o1 = __shfl_xor(m1, msk);
                const int   oi = __shfl_xor(i1k, msk);
                const float o2 = __shfl_xor(m2, msk);
                m2 = fminf(fminf(m2, o2), fmaxf(m1, o1));  // packed tie -> m2==m1
                const bool t = (o1 < m1) || (o1 == m1 && oi < i1k);
                i1k = t ? oi : i1k;
                m1  = fminf(m1, o1);
            }
            if (lrow == 0) {
                const int rw = st * 16 + lhi * 4 + r;
                Lm1[wv][rw] = m1; Lm2[wv][rw] = m2; Li[wv][rw] = i1k;
            }
        }
    __syncthreads();

    if (tid < 64) {
        float m1 = Lm1[0][tid], m2 = Lm2[0][tid];
        int   i1 = Li[0][tid];
#pragma unroll
        for (int w = 1; w < 4; ++w) {
            const float w1 = Lm1[w][tid], w2 = Lm2[w][tid];
            const int   wi = Li[w][tid];
            m2 = fminf(fminf(m2, w2), fmaxf(m1, w1));   // uses OLD m1
            if (w1 < m1) { m1 = w1; i1 = wi; }          // k-ranges ascend with w
        }
        const int row = n0 + tid;

        // exact rescore of the winner pair {i1, i1+16}
        float xr[CDIM];
        const float4* xp = reinterpret_cast<const float4*>(x + (size_t)row * CDIM);
#pragma unroll
        for (int j = 0; j < CDIM / 4; ++j) {
            const float4 v = xp[j];
            xr[4 * j + 0] = v.x; xr[4 * j + 1] = v.y;
            xr[4 * j + 2] = v.z; xr[4 * j + 3] = v.w;
        }
        float x2 = 0.f;
        {
#pragma clang fp contract(off)
#pragma unroll
            for (int j = 0; j < CDIM; ++j) x2 += xr[j] * xr[j];
        }
        const float d2a = exact_d2(xr, cb, c2f, x2, i1);
        const float d2b = exact_d2(xr, cb, c2f, x2, i1 + 16);
        int win; float d2w;
        if (d2b < d2a) { win = i1 + 16; d2w = d2b; }
        else           { win = i1;      d2w = d2a; }   // tie -> smaller index

        if (m2 - m1 > THR) {                 // certified: argmin is in the pair
            outidx[row] = (float)win;
            outd[row]   = sqrtf(fmaxf(d2w, 0.f));
            Lwin[tid]   = win;
        } else {                             // suspect: exact scan below
            const int s = atomicAdd(&s_cnt, 1);
            s_list[s] = tid;
        }
    }
    __syncthreads();

    // inline exact fallback: whole block scans all 4096 codes per suspect row
    const int ns = s_cnt;
    for (int s = 0; s < ns; ++s) {
        const int rl  = s_list[s];
        const int row = n0 + rl;
        float xr[CDIM];
        const float4* xp = reinterpret_cast<const float4*>(x + (size_t)row * CDIM);
#pragma unroll
        for (int j = 0; j < CDIM / 4; ++j) {
            const float4 v = xp[j];
            xr[4 * j + 0] = v.x; xr[4 * j + 1] = v.y;
            xr[4 * j + 2] = v.z; xr[4 * j + 3] = v.w;
        }
        float x2 = 0.f;
        {
#pragma clang fp contract(off)
#pragma unroll
            for (int j = 0; j < CDIM; ++j) x2 += xr[j] * xr[j];
        }
        float bd = FLT_MAX;
        int   bi = 0;
        for (int j = 0; j < 16; ++j) {
            const int k = j * 256 + tid;                 // ascending per thread
            const float d2v = exact_d2(xr, cb, c2f, x2, k);
            if (d2v < bd) { bd = d2v; bi = k; }          // strict <
        }
#pragma unroll
        for (int msk = 1; msk <= 32; msk <<= 1) {
            const float od = __shfl_xor(bd, msk);
            const int   oi = __shfl_xor(bi, msk);
            if (od < bd || (od == bd && oi < bi)) { bd = od; bi = oi; }
        }
        if (lane == 0) { swd[wv] = bd; swi[wv] = bi; }
        __syncthreads();
        if (tid == 0) {
            float bb = swd[0]; int bk = swi[0];
#pragma unroll
            for (int w = 1; w < 4; ++w)
                if (swd[w] < bb || (swd[w] == bb && swi[w] < bk)) { bb = swd[w]; bk = swi[w]; }
            outidx[row] = (float)bk;
            outd[row]   = sqrtf(fmaxf(bb, 0.f));
            Lwin[rl]    = bk;
        }
        __syncthreads();
    }

    // gather quantized = codebook[win]
    {
        const int r   = tid >> 2;
        const int seg = tid & 3;
        const int b   = Lwin[r];
        const float4* src = reinterpret_cast<const float4*>(cb + (size_t)b * CDIM) + seg * 4;
        float4* dst = reinterpret_cast<float4*>(outq + (size_t)(n0 + r) * CDIM) + seg * 4;
#pragma unroll
        for (int t = 0; t < 4; ++t) dst[t] = src[t];
    }
}

extern "C" void kernel_launch(void* const* d_in, const int* in_sizes, int n_in,
                              void* d_out, int out_size, void* d_ws, size_t ws_size,
                              hipStream_t stream) {
    const float* x  = (const float*)d_in[0];
    const float* cb = (const float*)d_in[1];
    float* outq   = (float*)d_out;
    float* outidx = outq + (size_t)NROWS * CDIM;
    float* outd   = outidx + NROWS;

    char* ws = (char*)d_ws;
    _Float16* ch  = (_Float16*)ws;                        // 512 KB
    _Float16* cm  = (_Float16*)(ws + 512 * 1024);         // 512 KB
    float*    c2f = (float*)(ws + 1024 * 1024);           // 16 KB

    prep_cb<<<KCB / 16, 256, 0, stream>>>(cb, ch, cm, c2f);
    vq_screen<<<NROWS / 64, 256, 0, stream>>>(x, cb, ch, cm, c2f, outq, outidx, outd);
}

// Round 10
// 255.664 us; speedup vs baseline: 1.9520x; 1.1270x over previous
//
#include <hip/hip_runtime.h>
#include <math.h>
#include <float.h>

// VectorQuantize, screen-and-rescore v5 = v3 numerics + per-wave LDS
// double-buffered B staging (global_load_lds, counted vmcnt, swizzled).
//  - 3-product fp16-split MFMA screen (hH + S1*(hM + mH); only mM dropped)
//  - pair-min tracking, pair-id packed in M1's low 5 mantissa bits
//  - certified rows (m2-m1 > THR): exact fp32 rescore of winner pair
//  - suspects: inline full exact fp32 scan by the whole block
// x [65536,64] f32, codebook [4096,64] f32.
// d_out (flat f32): quantized [N*64], idx [N] (as float), min_dists [N].

#define NROWS 65536
#define CDIM  64
#define KCB   4096
#define RSCALE 4096.0f
#define S1 (1.0f/4096.0f)
#define THR 1.5e-3f   // >= 2*(mM 2.6e-5 + acc-round 1e-4 + dd-fma 1.5e-5 + pack 2.4e-4)

#define WBYTES 16896     // per-wave LDS region: 2 buffers x 8448
#define BBYTES 8448      // buffer: ch 4096 | cm 4096 | c2 256

typedef _Float16 half8 __attribute__((ext_vector_type(8)));
typedef _Float16 half4 __attribute__((ext_vector_type(4)));
typedef float f32x4 __attribute__((ext_vector_type(4)));

#define MFMA16(A, B, C) __builtin_amdgcn_mfma_f32_16x16x32_f16(A, B, C, 0, 0, 0)

__device__ __forceinline__ void gll16(const void* g, void* l) {
    __builtin_amdgcn_global_load_lds(
        (const __attribute__((address_space(1))) void*)g,
        (__attribute__((address_space(3))) void*)l, 16, 0, 0);
}
__device__ __forceinline__ void gll4(const void* g, void* l) {
    __builtin_amdgcn_global_load_lds(
        (const __attribute__((address_space(1))) void*)g,
        (__attribute__((address_space(3))) void*)l, 4, 0, 0);
}

#define WAITV(N) do { asm volatile("s_waitcnt vmcnt(" #N ")" ::: "memory"); \
                      __builtin_amdgcn_sched_barrier(0); } while (0)

__device__ __forceinline__ float exact_d2(const float* __restrict__ xr, const float* __restrict__ cb,
                                          const float* __restrict__ c2f, float x2, int k) {
    const float4* cp4 = reinterpret_cast<const float4*>(cb + (size_t)k * CDIM);
    float da = 0.f, db = 0.f;
#pragma unroll
    for (int j4 = 0; j4 < CDIM / 4; ++j4) {
        float4 cv = cp4[j4];
        da = fmaf(xr[4 * j4 + 0], cv.x, da);
        db = fmaf(xr[4 * j4 + 1], cv.y, db);
        da = fmaf(xr[4 * j4 + 2], cv.z, da);
        db = fmaf(xr[4 * j4 + 3], cv.w, db);
    }
    const float dot = da + db;
    return fmaf(-2.f, dot, x2) + c2f[k];
}

// ---- prep: fp16 split codebook (ch, cm) + c2f = ||c_k||^2 ----
__global__ __launch_bounds__(256) void prep_cb(const float* __restrict__ cb,
                                               _Float16* __restrict__ ch,
                                               _Float16* __restrict__ cm,
                                               float* __restrict__ c2f) {
    const int row = blockIdx.x * 16 + (threadIdx.x >> 4);
    const int j   = threadIdx.x & 15;
    const float4 v = *reinterpret_cast<const float4*>(cb + (size_t)row * CDIM + j * 4);
    float s;
    {
#pragma clang fp contract(off)
        s = v.x * v.x + v.y * v.y + v.z * v.z + v.w * v.w;
    }
    s += __shfl_xor(s, 1);
    s += __shfl_xor(s, 2);
    s += __shfl_xor(s, 4);
    s += __shfl_xor(s, 8);
    if (j == 0) c2f[row] = s;
    float e[4] = {v.x, v.y, v.z, v.w};
    half4 h, m;
#pragma unroll
    for (int t = 0; t < 4; ++t) {
        _Float16 hv = (_Float16)e[t];
        h[t] = hv;
        m[t] = (_Float16)((e[t] - (float)hv) * RSCALE);  // exact residual, scaled
    }
    *reinterpret_cast<half4*>(ch + (size_t)row * CDIM + j * 4) = h;
    *reinterpret_cast<half4*>(cm + (size_t)row * CDIM + j * 4) = m;
}

// ---- main: LDS-pipelined 3-product screen + certify + rescore + fallback ----
__global__ __launch_bounds__(256, 2) void vq_screen(
    const float* __restrict__ x, const float* __restrict__ cb,
    const _Float16* __restrict__ ch, const _Float16* __restrict__ cm,
    const float* __restrict__ c2f,
    float* __restrict__ outq, float* __restrict__ outidx, float* __restrict__ outd) {

    const int tid  = threadIdx.x;
    const int lane = tid & 63;
    const int wv   = __builtin_amdgcn_readfirstlane(tid >> 6);
    const int lrow = lane & 15;
    const int lhi  = lane >> 4;
    const int n0   = blockIdx.x * 64;
    const int kbase = wv * 1024;        // each wave screens a k-quarter

    __shared__ __align__(16) char lds_raw[4 * WBYTES];   // 67.5 KB staging
    __shared__ float Lm1[4][64], Lm2[4][64];
    __shared__ int   Li[4][64];
    __shared__ int   Lwin[64];
    __shared__ int   s_cnt;
    __shared__ int   s_list[64];
    __shared__ float swd[4];
    __shared__ int   swi[4];
    if (tid == 0) s_cnt = 0;

    // swizzled within-1KB source offset: LDS[p] = SRC[p ^ (((p>>7)&7)<<4)]
    const int so = 16 * (lane ^ (lane >> 3));

#define STAGE(KT2, BUF) do { \
        char* lb_ = lds_raw + wv * WBYTES + (BUF) * BBYTES; \
        const size_t tb_ = (size_t)(kbase + (KT2) * 32) * 128; \
        const char* cs_ = (const char*)ch + tb_ + so; \
        const char* ms_ = (const char*)cm + tb_ + so; \
        gll16(cs_,        lb_);        \
        gll16(cs_ + 1024, lb_ + 1024); \
        gll16(cs_ + 2048, lb_ + 2048); \
        gll16(cs_ + 3072, lb_ + 3072); \
        gll16(ms_,        lb_ + 4096); \
        gll16(ms_ + 1024, lb_ + 5120); \
        gll16(ms_ + 2048, lb_ + 6144); \
        gll16(ms_ + 3072, lb_ + 7168); \
        gll4((const char*)c2f + (size_t)(kbase + (KT2) * 32 + (lane & 31)) * 4, lb_ + 8192); \
    } while (0)

    int cur = 0;
    STAGE(0, 0);   // tile-0 staging flies under the A-setup below

    // A fragments: h and scaled residual m (x rows n0..n0+63; layout HW-proven)
    half8 afh[4][2], afm[4][2];
#pragma unroll
    for (int st = 0; st < 4; ++st) {
#pragma unroll
        for (int cs = 0; cs < 2; ++cs) {
            const float* xp = x + (size_t)(n0 + st * 16 + lrow) * CDIM + cs * 32 + lhi * 8;
            const float4 a = *reinterpret_cast<const float4*>(xp);
            const float4 b = *reinterpret_cast<const float4*>(xp + 4);
            float e[8] = {a.x, a.y, a.z, a.w, b.x, b.y, b.z, b.w};
#pragma unroll
            for (int jj = 0; jj < 8; ++jj) {
                _Float16 hv = (_Float16)e[jj];
                afh[st][cs][jj] = hv;
                afm[st][cs][jj] = (_Float16)((e[jj] - (float)hv) * RSCALE);
            }
        }
    }

    const f32x4 zz = {0.f, 0.f, 0.f, 0.f};
    float M1[4][4], M2[4][4];     // M1 carries pair-id in low 5 mantissa bits
#pragma unroll
    for (int st = 0; st < 4; ++st)
#pragma unroll
        for (int r = 0; r < 4; ++r) { M1[st][r] = FLT_MAX; M2[st][r] = FLT_MAX; }

    const int rowb = lrow * 128;
    const int swz  = (lrow & 7) << 4;
    const int o00  = (lhi * 16) ^ swz;        // k-half 0 within row
    const int o64  = (64 + lhi * 16) ^ swz;   // k-half 1 within row

    for (int kt2 = 0; kt2 < 32; ++kt2) {     // 32-code tile pair per iter
        if (kt2 < 31) { STAGE(kt2 + 1, cur ^ 1); WAITV(9); }
        else          { WAITV(0); }

        const char* rb = lds_raw + wv * WBYTES + cur * BBYTES;
        const half8 bh0 = *(const half8*)(rb + rowb + o00);
        const half8 bh1 = *(const half8*)(rb + rowb + o64);
        const half8 bh2 = *(const half8*)(rb + 2048 + rowb + o00);
        const half8 bh3 = *(const half8*)(rb + 2048 + rowb + o64);
        const half8 bm0 = *(const half8*)(rb + 4096 + rowb + o00);
        const half8 bm1 = *(const half8*)(rb + 4096 + rowb + o64);
        const half8 bm2 = *(const half8*)(rb + 6144 + rowb + o00);
        const half8 bm3 = *(const half8*)(rb + 6144 + rowb + o64);
        const float c2a = *(const float*)(rb + 8192 + lrow * 4);
        const float c2b = *(const float*)(rb + 8192 + 64 + lrow * 4);

        // ---- tile 0 (codes kt2*32 + lrow) ----
        float t0[4][4];
        {
            f32x4 a0[4], a1[4];
#pragma unroll
            for (int st = 0; st < 4; ++st) {
                a0[st] = MFMA16(afh[st][0], bh0, zz);
                a1[st] = MFMA16(afh[st][0], bm0, zz);
            }
#pragma unroll
            for (int st = 0; st < 4; ++st) {
                a0[st] = MFMA16(afh[st][1], bh1, a0[st]);
                a1[st] = MFMA16(afh[st][1], bm1, a1[st]);
            }
#pragma unroll
            for (int st = 0; st < 4; ++st) {
                a1[st] = MFMA16(afm[st][0], bh0, a1[st]);
                a1[st] = MFMA16(afm[st][1], bh1, a1[st]);
            }
#pragma unroll
            for (int st = 0; st < 4; ++st)
#pragma unroll
                for (int r = 0; r < 4; ++r)
                    t0[st][r] = fmaf(-2.f * S1, a1[st][r], fmaf(-2.f, a0[st][r], c2a));
        }
        // ---- tile 1 (codes +16) + pair update ----
        {
            f32x4 a0[4], a1[4];
#pragma unroll
            for (int st = 0; st < 4; ++st) {
                a0[st] = MFMA16(afh[st][0], bh2, zz);
                a1[st] = MFMA16(afh[st][0], bm2, zz);
            }
#pragma unroll
            for (int st = 0; st < 4; ++st) {
                a0[st] = MFMA16(afh[st][1], bh3, a0[st]);
                a1[st] = MFMA16(afh[st][1], bm3, a1[st]);
            }
#pragma unroll
            for (int st = 0; st < 4; ++st) {
                a1[st] = MFMA16(afm[st][0], bh2, a1[st]);
                a1[st] = MFMA16(afm[st][1], bh3, a1[st]);
            }
#pragma unroll
            for (int st = 0; st < 4; ++st)
#pragma unroll
                for (int r = 0; r < 4; ++r) {
                    const float dd1 = fmaf(-2.f * S1, a1[st][r], fmaf(-2.f, a0[st][r], c2b));
                    const float pm  = fminf(t0[st][r], dd1);
                    const float pmp = __uint_as_float((__float_as_uint(pm) & ~31u) | (unsigned)kt2);
                    M2[st][r] = fminf(M2[st][r], fmaxf(pmp, M1[st][r]));  // OLD M1
                    M1[st][r] = fminf(M1[st][r], pmp);
                }
        }
        cur ^= 1;
    }
#undef STAGE

    // butterfly-merge the 16 code-slot lanes (lrow) of each lhi group
#pragma unroll
    for (int st = 0; st < 4; ++st)
#pragma unroll
        for (int r = 0; r < 4; ++r) {
            const unsigned kt2e = __float_as_uint(M1[st][r]) & 31u;
            int   i1k = kbase + (int)kt2e * 32 + lrow;   // pair-base code id
            float m1  = M1[st][r], m2 = M2[st][r];
#pragma unroll
            for (int msk = 1; msk <= 8; msk <<= 1) {
                const float o1 = __shfl_xor(m1, msk);
                const int   oi = __shfl_xor(i1k, msk);
                const float o2 = __shfl_xor(m2, msk);
                m2 = fminf(fminf(m2, o2), fmaxf(m1, o1));  // packed tie -> m2==m1
                const bool t = (o1 < m1) || (o1 == m1 && oi < i1k);
                i1k = t ? oi : i1k;
                m1  = fminf(m1, o1);
            }
            if (lrow == 0) {
                const int rw = st * 16 + lhi * 4 + r;
                Lm1[wv][rw] = m1; Lm2[wv][rw] = m2; Li[wv][rw] = i1k;
            }
        }
    __syncthreads();

    if (tid < 64) {
        float m1 = Lm1[0][tid], m2 = Lm2[0][tid];
        int   i1 = Li[0][tid];
#pragma unroll
        for (int w = 1; w < 4; ++w) {
            const float w1 = Lm1[w][tid], w2 = Lm2[w][tid];
            const int   wi = Li[w][tid];
            m2 = fminf(fminf(m2, w2), fmaxf(m1, w1));   // uses OLD m1
            if (w1 < m1) { m1 = w1; i1 = wi; }          // k-ranges ascend with w
        }
        const int row = n0 + tid;

        // exact rescore of the winner pair {i1, i1+16}
        float xr[CDIM];
        const float4* xp = reinterpret_cast<const float4*>(x + (size_t)row * CDIM);
#pragma unroll
        for (int j = 0; j < CDIM / 4; ++j) {
            const float4 v = xp[j];
            xr[4 * j + 0] = v.x; xr[4 * j + 1] = v.y;
            xr[4 * j + 2] = v.z; xr[4 * j + 3] = v.w;
        }
        float x2 = 0.f;
        {
#pragma clang fp contract(off)
#pragma unroll
            for (int j = 0; j < CDIM; ++j) x2 += xr[j] * xr[j];
        }
        const float d2a = exact_d2(xr, cb, c2f, x2, i1);
        const float d2b = exact_d2(xr, cb, c2f, x2, i1 + 16);
        int win; float d2w;
        if (d2b < d2a) { win = i1 + 16; d2w = d2b; }
        else           { win = i1;      d2w = d2a; }   // tie -> smaller index

        if (m2 - m1 > THR) {                 // certified: argmin is in the pair
            outidx[row] = (float)win;
            outd[row]   = sqrtf(fmaxf(d2w, 0.f));
            Lwin[tid]   = win;
        } else {                             // suspect: exact scan below
            const int s = atomicAdd(&s_cnt, 1);
            s_list[s] = tid;
        }
    }
    __syncthreads();

    // inline exact fallback: whole block scans all 4096 codes per suspect row
    const int ns = s_cnt;
    for (int s = 0; s < ns; ++s) {
        const int rl  = s_list[s];
        const int row = n0 + rl;
        float xr[CDIM];
        const float4* xp = reinterpret_cast<const float4*>(x + (size_t)row * CDIM);
#pragma unroll
        for (int j = 0; j < CDIM / 4; ++j) {
            const float4 v = xp[j];
            xr[4 * j + 0] = v.x; xr[4 * j + 1] = v.y;
            xr[4 * j + 2] = v.z; xr[4 * j + 3] = v.w;
        }
        float x2 = 0.f;
        {
#pragma clang fp contract(off)
#pragma unroll
            for (int j = 0; j < CDIM; ++j) x2 += xr[j] * xr[j];
        }
        float bd = FLT_MAX;
        int   bi = 0;
        for (int j = 0; j < 16; ++j) {
            const int k = j * 256 + tid;                 // ascending per thread
            const float d2v = exact_d2(xr, cb, c2f, x2, k);
            if (d2v < bd) { bd = d2v; bi = k; }          // strict <
        }
#pragma unroll
        for (int msk = 1; msk <= 32; msk <<= 1) {
            const float od = __shfl_xor(bd, msk);
            const int   oi = __shfl_xor(bi, msk);
            if (od < bd || (od == bd && oi < bi)) { bd = od; bi = oi; }
        }
        if (lane == 0) { swd[wv] = bd; swi[wv] = bi; }
        __syncthreads();
        if (tid == 0) {
            float bb = swd[0]; int bk = swi[0];
#pragma unroll
            for (int w = 1; w < 4; ++w)
                if (swd[w] < bb || (swd[w] == bb && swi[w] < bk)) { bb = swd[w]; bk = swi[w]; }
            outidx[row] = (float)bk;
            outd[row]   = sqrtf(fmaxf(bb, 0.f));
            Lwin[rl]    = bk;
        }
        __syncthreads();
    }

    // gather quantized = codebook[win]
    {
        const int r   = tid >> 2;
        const int seg = tid & 3;
        const int b   = Lwin[r];
        const float4* src = reinterpret_cast<const float4*>(cb + (size_t)b * CDIM) + seg * 4;
        float4* dst = reinterpret_cast<float4*>(outq + (size_t)(n0 + r) * CDIM) + seg * 4;
#pragma unroll
        for (int t = 0; t < 4; ++t) dst[t] = src[t];
    }
}

extern "C" void kernel_launch(void* const* d_in, const int* in_sizes, int n_in,
                              void* d_out, int out_size, void* d_ws, size_t ws_size,
                              hipStream_t stream) {
    const float* x  = (const float*)d_in[0];
    const float* cb = (const float*)d_in[1];
    float* outq   = (float*)d_out;
    float* outidx = outq + (size_t)NROWS * CDIM;
    float* outd   = outidx + NROWS;

    char* ws = (char*)d_ws;
    _Float16* ch  = (_Float16*)ws;                        // 512 KB
    _Float16* cm  = (_Float16*)(ws + 512 * 1024);         // 512 KB
    float*    c2f = (float*)(ws + 1024 * 1024);           // 16 KB

    prep_cb<<<KCB / 16, 256, 0, stream>>>(cb, ch, cm, c2f);
    vq_screen<<<NROWS / 64, 256, 0, stream>>>(x, cb, ch, cm, c2f, outq, outidx, outd);
}